// Round 1
// baseline (1065.419 us; speedup 1.0000x reference)
//
#include <hip/hip_runtime.h>
#include <hip/hip_bf16.h>

// EventEncoder: gather -> [E,129]@W1 -> LN -> [E,256]@W2 -> 4-way scatter-add
// D=64, d_h=256, d_in=129 hardcoded (derived sizes asserted host-side by construction).

#define TILE_E 32

__global__ void zero_f4_kernel(float4* p, int n4) {
    int i = blockIdx.x * 256 + threadIdx.x;
    int stride = gridDim.x * 256;
    float4 z = make_float4(0.f, 0.f, 0.f, 0.f);
    for (; i < n4; i += stride) p[i] = z;
}

__global__ __launch_bounds__(256, 2)
void encode_scatter_kernel(const int* __restrict__ users, const int* __restrict__ items,
                           const float* __restrict__ msgs,
                           const float* __restrict__ uemb, const float* __restrict__ iemb,
                           const float* __restrict__ W1, const float* __restrict__ b1,
                           const float* __restrict__ ln_g, const float* __restrict__ ln_b,
                           const float* __restrict__ W2, const float* __restrict__ b2,
                           float* __restrict__ out, float* __restrict__ glob,
                           int E, int num_nodes, int bs, long out_half) {
    __shared__ float xs[TILE_E][132];   // 129 used, row stride 528B (16B aligned)
    __shared__ float hs[TILE_E][256];
    __shared__ float gacc[2 * 32 * 64]; // [user/item][b<=32][d=64]

    const int tid = threadIdx.x;
    const int j = tid;            // output column 0..255
    const int grp = tid >> 6;     // wave id: 0=uu,1=iu,2=ug,3=ig
    const int d = tid & 63;

    for (int i = tid; i < 2 * 32 * 64; i += 256) gacc[i] = 0.f;

    const float b1v = b1[j];
    const float b2v = b2[j];

    const int nTiles = (E + TILE_E - 1) / TILE_E;
    for (int tile = blockIdx.x; tile < nTiles; tile += gridDim.x) {
        const int e0 = tile * TILE_E;
        const int ne = min(TILE_E, E - e0);

        __syncthreads();  // all prior-tile readers done before restaging

        // ---- stage x[e][0..128] into LDS (float4 gathers) ----
        for (int idx = tid; idx < TILE_E * 32; idx += 256) {
            int e = idx >> 5, q = idx & 31;
            float4 v = make_float4(0.f, 0.f, 0.f, 0.f);
            if (e < ne) {
                int ev = e0 + e;
                if (q < 16) {
                    int u = users[ev] % num_nodes;
                    v = ((const float4*)uemb)[(size_t)u * 16 + q];
                } else {
                    int it = items[ev] % num_nodes;
                    v = ((const float4*)iemb)[(size_t)it * 16 + (q - 16)];
                }
            }
            *(float4*)&xs[e][q << 2] = v;
        }
        if (tid < TILE_E) {
            xs[tid][128] = (tid < ne) ? msgs[e0 + tid] : 0.f;
        }
        __syncthreads();

        // ---- GEMM1: h[e][j] = b1[j] + sum_k x[e][k]*W1[k][j] ----
        float acc[TILE_E];
#pragma unroll
        for (int e = 0; e < TILE_E; e++) acc[e] = b1v;

        for (int kg = 0; kg < 32; kg++) {
            const float* wp = W1 + (kg << 2) * 256 + j;
            float4 w;
            w.x = wp[0]; w.y = wp[256]; w.z = wp[512]; w.w = wp[768];
#pragma unroll
            for (int e = 0; e < TILE_E; e++) {
                float4 xv = *(const float4*)&xs[e][kg << 2];
                acc[e] = fmaf(xv.x, w.x, acc[e]);
                acc[e] = fmaf(xv.y, w.y, acc[e]);
                acc[e] = fmaf(xv.z, w.z, acc[e]);
                acc[e] = fmaf(xv.w, w.w, acc[e]);
            }
        }
        {
            float w128 = W1[128 * 256 + j];
#pragma unroll
            for (int e = 0; e < TILE_E; e++) acc[e] = fmaf(xs[e][128], w128, acc[e]);
        }
#pragma unroll
        for (int e = 0; e < TILE_E; e++) hs[e][j] = acc[e];
        __syncthreads();

        // ---- LayerNorm per event row; wave w handles 8 rows ----
        {
            const int w = tid >> 6, lane = tid & 63;
            for (int t = 0; t < 8; t++) {
                int e = w * 8 + t;
                float4 hv = *(const float4*)&hs[e][lane << 2];
                float s1 = hv.x + hv.y + hv.z + hv.w;
                float s2 = hv.x * hv.x + hv.y * hv.y + hv.z * hv.z + hv.w * hv.w;
                for (int off = 32; off; off >>= 1) {
                    s1 += __shfl_xor(s1, off);
                    s2 += __shfl_xor(s2, off);
                }
                float mu = s1 * (1.f / 256.f);
                float var = s2 * (1.f / 256.f) - mu * mu;
                float rs = rsqrtf(var + 1e-5f);
                float4 g = *(const float4*)&ln_g[lane << 2];
                float4 bb = *(const float4*)&ln_b[lane << 2];
                hv.x = (hv.x - mu) * rs * g.x + bb.x;
                hv.y = (hv.y - mu) * rs * g.y + bb.y;
                hv.z = (hv.z - mu) * rs * g.z + bb.z;
                hv.w = (hv.w - mu) * rs * g.w + bb.w;
                *(float4*)&hs[e][lane << 2] = hv;
            }
        }
        __syncthreads();

        // ---- GEMM2: enc[e][j] = b2[j] + sum_k hn[e][k]*W2[k][j] ----
#pragma unroll
        for (int e = 0; e < TILE_E; e++) acc[e] = b2v;

        for (int kg = 0; kg < 64; kg++) {
            const float* wp = W2 + (kg << 2) * 256 + j;
            float4 w;
            w.x = wp[0]; w.y = wp[256]; w.z = wp[512]; w.w = wp[768];
#pragma unroll
            for (int e = 0; e < TILE_E; e++) {
                float4 hv = *(const float4*)&hs[e][kg << 2];
                acc[e] = fmaf(hv.x, w.x, acc[e]);
                acc[e] = fmaf(hv.y, w.y, acc[e]);
                acc[e] = fmaf(hv.z, w.z, acc[e]);
                acc[e] = fmaf(hv.w, w.w, acc[e]);
            }
        }

        // ---- scatter: wave0->uu(out), wave1->iu(out), wave2->ug(LDS), wave3->ig(LDS) ----
#pragma unroll
        for (int e = 0; e < TILE_E; e++) {
            int ev = e0 + e;
            if (ev < E) {
                if (grp == 0) {
                    int u = users[ev];
                    int b = u % bs, node = u / bs;
                    atomicAdd(&out[(size_t)b * num_nodes * 64 + (size_t)node * 64 + d], acc[e]);
                } else if (grp == 1) {
                    int it = items[ev];
                    int b = it % bs, node = it / bs;
                    atomicAdd(&out[(size_t)out_half + (size_t)b * num_nodes * 64 + (size_t)node * 64 + d], acc[e]);
                } else if (grp == 2) {
                    int u = users[ev];
                    atomicAdd(&gacc[(u % bs) * 64 + d], acc[e]);
                } else {
                    int it = items[ev];
                    atomicAdd(&gacc[2048 + (it % bs) * 64 + d], acc[e]);
                }
            }
        }
    }

    // ---- flush block-local global-mean accumulators ----
    __syncthreads();
    for (int i = tid; i < 2 * 32 * 64; i += 256) {
        float v = gacc[i];
        if (v != 0.f) atomicAdd(&glob[i], v);
    }
}

__global__ void finalize_kernel(float* __restrict__ out, const float* __restrict__ glob,
                                long out_half, long nnD, float inv_nodes, int n4) {
    int i4 = blockIdx.x * 256 + threadIdx.x;
    int stride = gridDim.x * 256;
    for (; i4 < n4; i4 += stride) {
        long i = (long)i4 * 4;
        int half = (i >= out_half) ? 1 : 0;
        long r = half ? (i - out_half) : i;
        int b = (int)(r / nnD);
        int dq = (int)(i & 63);
        float4 gv = *(const float4*)&glob[half * 2048 + b * 64 + dq];
        float4 o = ((float4*)out)[i4];
        o.x += gv.x * inv_nodes;
        o.y += gv.y * inv_nodes;
        o.z += gv.z * inv_nodes;
        o.w += gv.w * inv_nodes;
        ((float4*)out)[i4] = o;
    }
}

extern "C" void kernel_launch(void* const* d_in, const int* in_sizes, int n_in,
                              void* d_out, int out_size, void* d_ws, size_t ws_size,
                              hipStream_t stream) {
    const int* users = (const int*)d_in[0];
    const int* items = (const int*)d_in[1];
    const float* msgs = (const float*)d_in[2];
    // d_in[3] = bs scalar on device (unused; derived from sizes)
    const float* uemb = (const float*)d_in[4];
    const float* iemb = (const float*)d_in[5];
    const float* W1 = (const float*)d_in[6];
    const float* b1 = (const float*)d_in[7];
    const float* ln_g = (const float*)d_in[8];
    const float* ln_b = (const float*)d_in[9];
    const float* W2 = (const float*)d_in[10];
    const float* b2 = (const float*)d_in[11];

    float* out = (float*)d_out;
    float* glob = (float*)d_ws;  // [2][32][64] f32 = 16KB

    const int E = in_sizes[0];
    const int dh = in_sizes[7];          // 256
    const int D = dh / 4;                // 64
    const int num_nodes = in_sizes[4] / D;
    const long out_half = (long)out_size / 2;
    const int bs = (int)(out_half / ((long)num_nodes * D));

    // zero d_out and glob accumulator every call (deterministic)
    zero_f4_kernel<<<2048, 256, 0, stream>>>((float4*)out, out_size / 4);
    zero_f4_kernel<<<4, 256, 0, stream>>>((float4*)glob, (2 * 32 * 64) / 4);

    encode_scatter_kernel<<<512, 256, 0, stream>>>(
        users, items, msgs, uemb, iemb, W1, b1, ln_g, ln_b, W2, b2,
        out, glob, E, num_nodes, bs, out_half);

    finalize_kernel<<<2048, 256, 0, stream>>>(out, glob, out_half,
                                              (long)num_nodes * 64, 1.0f / num_nodes,
                                              out_size / 4);
}

// Round 2
// 685.202 us; speedup vs baseline: 1.5549x; 1.5549x over previous
//
#include <hip/hip_runtime.h>
#include <hip/hip_bf16.h>

// EventEncoder via bf16 MFMA: gather -> [64x128]@W1(+msg rank-1) -> LN -> [64x256]@W2 -> scatter
// D=64, d_h=256, d_in=129. TILE=64 events/block, 4 waves, 16x16x32 bf16 MFMA.

typedef __attribute__((ext_vector_type(8))) short bf8_t;   // 8 bf16 = 4 VGPRs
typedef __attribute__((ext_vector_type(4))) float f32x4;

union FragU { bf8_t f; unsigned int u[4]; };

static __device__ __forceinline__ unsigned short f2bf(float f) {
    unsigned int x = __float_as_uint(f);
    return (unsigned short)((x + 0x7fffu + ((x >> 16) & 1u)) >> 16);
}
#define B2F_LO(u) __uint_as_float((u) << 16)
#define B2F_HI(u) __uint_as_float((u) & 0xffff0000u)

__global__ void zero_f4_kernel(float4* p, int n4) {
    int i = blockIdx.x * 256 + threadIdx.x;
    int stride = gridDim.x * 256;
    float4 z = make_float4(0.f, 0.f, 0.f, 0.f);
    for (; i < n4; i += stride) p[i] = z;
}

// Pre-convert W1/W2 (f32) into fragment-ordered bf16 in ws.
// Frag layout: lane l (0..63): n = nt*16 + (l&15); g = l>>4;
//   elems e=0..3: k = ks*32 + 4g+e ; e=4..7: k = ks*32 + 16 + 4g + (e-4)
__global__ void convert_w_kernel(const float* __restrict__ W1, const float* __restrict__ W2,
                                 unsigned short* __restrict__ w1f, unsigned short* __restrict__ w2f) {
    int idx = blockIdx.x * 256 + threadIdx.x;
    if (idx < 4096) {               // W1: 16 nt * 4 ks * 64 lanes
        int l = idx & 63, fr = idx >> 6;
        int ks = fr & 3, nt = fr >> 2;
        int n = nt * 16 + (l & 15), g = l >> 4;
        unsigned short v[8];
#pragma unroll
        for (int e = 0; e < 8; e++) {
            int k = ks * 32 + ((e < 4) ? (4 * g + e) : (16 + 4 * g + (e - 4)));
            v[e] = f2bf(W1[k * 256 + n]);
        }
        uint4 pk;
        pk.x = (unsigned)v[0] | ((unsigned)v[1] << 16);
        pk.y = (unsigned)v[2] | ((unsigned)v[3] << 16);
        pk.z = (unsigned)v[4] | ((unsigned)v[5] << 16);
        pk.w = (unsigned)v[6] | ((unsigned)v[7] << 16);
        *(uint4*)&w1f[idx * 8] = pk;
    } else if (idx < 12288) {       // W2: 16 nt * 8 ks * 64 lanes
        int t = idx - 4096;
        int l = t & 63, fr = t >> 6;
        int ks = fr & 7, nt = fr >> 3;
        int n = nt * 16 + (l & 15), g = l >> 4;
        unsigned short v[8];
#pragma unroll
        for (int e = 0; e < 8; e++) {
            int k = ks * 32 + ((e < 4) ? (4 * g + e) : (16 + 4 * g + (e - 4)));
            v[e] = f2bf(W2[k * 256 + n]);
        }
        uint4 pk;
        pk.x = (unsigned)v[0] | ((unsigned)v[1] << 16);
        pk.y = (unsigned)v[2] | ((unsigned)v[3] << 16);
        pk.z = (unsigned)v[4] | ((unsigned)v[5] << 16);
        pk.w = (unsigned)v[6] | ((unsigned)v[7] << 16);
        *(uint4*)&w2f[t * 8] = pk;
    }
}

__global__ __launch_bounds__(256, 2)
void encode_mfma_kernel(const int* __restrict__ users, const int* __restrict__ items,
                        const float* __restrict__ msgs,
                        const float* __restrict__ uemb, const float* __restrict__ iemb,
                        const float* __restrict__ W1, const float* __restrict__ b1,
                        const float* __restrict__ ln_g, const float* __restrict__ ln_b,
                        const float* __restrict__ b2,
                        const unsigned short* __restrict__ w1f, const unsigned short* __restrict__ w2f,
                        float* __restrict__ out, float* __restrict__ glob,
                        int E, int num_nodes, int bs, long out_half) {
    // xhb: GEMM1 phase uses first 64*128 as x (bf16, swizzled); then whole 64*256 as h/hn.
    __shared__ __align__(16) unsigned short xhb[64 * 256];   // 32 KB
    __shared__ __align__(16) float gacc[4096];               // 16 KB  [2][32][64]
    __shared__ __align__(16) float msgs_s[64];
    __shared__ __align__(16) int ubase_s[64], ibase_s[64];   // base | (b<<26)

    const int tid = threadIdx.x;
    const int w = tid >> 6;         // wave 0..3 -> owns output cols w*64..w*64+63
    const int l = tid & 63;
    const int g = l >> 4;           // 0..3
    const int m16 = l & 15;
    const int nnD = num_nodes * 64;

    for (int i = tid; i < 4096; i += 256) gacc[i] = 0.f;

    // hoist W1 fragments (per wave: its 4 Ntiles x 4 Ksteps = 64 VGPRs)
    bf8_t w1frag[4][4];
#pragma unroll
    for (int ntl = 0; ntl < 4; ntl++)
#pragma unroll
        for (int ks = 0; ks < 4; ks++)
            w1frag[ntl][ks] = *(const bf8_t*)&w1f[(((w * 4 + ntl) * 4 + ks) * 64 + l) * 8];

    float b1v[4], w128v[4], b2v[4];
#pragma unroll
    for (int ntl = 0; ntl < 4; ntl++) {
        int j = w * 64 + ntl * 16 + m16;
        b1v[ntl] = b1[j];
        w128v[ntl] = W1[128 * 256 + j];   // msg column of W1
        b2v[ntl] = b2[j];
    }
    float* outi = out + out_half;

    const int nTiles = (E + 63) >> 6;
    for (int tile = blockIdx.x; tile < nTiles; tile += gridDim.x) {
        const int e0 = tile << 6;
        __syncthreads();   // (A) prev tile's GEMM2 readers done

        // ---- stage per-event scalars ----
        if (tid < 64) {
            int ev = e0 + tid;
            if (ev < E) {
                int u = users[ev], it = items[ev];
                int ub = u % bs, un = u / bs, ib = it % bs, in_ = it / bs;
                ubase_s[tid] = (ub * nnD + un * 64) | (ub << 26);
                ibase_s[tid] = (ib * nnD + in_ * 64) | (ib << 26);
                msgs_s[tid] = msgs[ev];
            } else {
                ubase_s[tid] = -1; ibase_s[tid] = -1; msgs_s[tid] = 0.f;
            }
        }
        // ---- stage x as bf16, swizzled: byte_in_row ^= (e&7)<<4, rows 256B ----
        for (int idx = tid; idx < 64 * 32; idx += 256) {
            int e = idx >> 5, q = idx & 31;
            int ev = e0 + e;
            float4 v = make_float4(0.f, 0.f, 0.f, 0.f);
            if (ev < E) {
                if (q < 16) { int u = users[ev] % num_nodes; v = ((const float4*)uemb)[(long)u * 16 + q]; }
                else        { int it = items[ev] % num_nodes; v = ((const float4*)iemb)[(long)it * 16 + (q - 16)]; }
            }
            ushort4 p;
            p.x = f2bf(v.x); p.y = f2bf(v.y); p.z = f2bf(v.z); p.w = f2bf(v.w);
            int byte = (q * 8) ^ ((e & 7) << 4);
            *(ushort4*)&xhb[e * 128 + (byte >> 1)] = p;
        }
        __syncthreads();   // (B)

        // ---- GEMM1: acc[mt][ntl] over K=128, init with b1 + msg*W1[128] ----
        f32x4 acc[4][4];
#pragma unroll
        for (int mt = 0; mt < 4; mt++) {
            const float* mgp = &msgs_s[mt * 16 + 4 * g];
            float mg[4] = {mgp[0], mgp[1], mgp[2], mgp[3]};
#pragma unroll
            for (int ntl = 0; ntl < 4; ntl++) {
                f32x4 a;
#pragma unroll
                for (int r = 0; r < 4; r++) a[r] = fmaf(mg[r], w128v[ntl], b1v[ntl]);
                acc[mt][ntl] = a;
            }
        }
#pragma unroll
        for (int ks = 0; ks < 4; ks++) {
            FragU a[4];
#pragma unroll
            for (int mt = 0; mt < 4; mt++) {
                int i = mt * 16 + m16;
                int bir0 = (ks * 64 + 8 * g) ^ ((i & 7) << 4);
                int bir1 = (ks * 64 + 32 + 8 * g) ^ ((i & 7) << 4);
                uint2 c0 = *(const uint2*)&xhb[i * 128 + (bir0 >> 1)];
                uint2 c1 = *(const uint2*)&xhb[i * 128 + (bir1 >> 1)];
                a[mt].u[0] = c0.x; a[mt].u[1] = c0.y; a[mt].u[2] = c1.x; a[mt].u[3] = c1.y;
            }
#pragma unroll
            for (int ntl = 0; ntl < 4; ntl++)
#pragma unroll
                for (int mt = 0; mt < 4; mt++)
                    acc[mt][ntl] = __builtin_amdgcn_mfma_f32_16x16x32_bf16(
                        a[mt].f, w1frag[ntl][ks], acc[mt][ntl], 0, 0, 0);
        }
        __syncthreads();   // (C) all GEMM1 x-reads done; xhb becomes h buffer

        // ---- epilogue: h -> bf16 into xhb rows of 256, swizzle (e&15)<<4 ----
#pragma unroll
        for (int mt = 0; mt < 4; mt++)
#pragma unroll
            for (int ntl = 0; ntl < 4; ntl++)
#pragma unroll
                for (int r = 0; r < 4; r++) {
                    int e = mt * 16 + 4 * g + r;
                    int j = w * 64 + ntl * 16 + m16;
                    int byte = (2 * j) ^ ((e & 15) << 4);
                    xhb[e * 256 + (byte >> 1)] = f2bf(acc[mt][ntl][r]);
                }
        __syncthreads();   // (D)

        // ---- LayerNorm in place: wave w rows w*16..w*16+15, 2 rows/iter ----
#pragma unroll
        for (int it = 0; it < 8; it++) {
            int e = w * 16 + it * 2 + (l >> 5);
            int slot = l & 31;
            int byte = (slot * 16) ^ ((e & 15) << 4);
            uint4 hv = *(const uint4*)&xhb[e * 256 + (byte >> 1)];
            float f0 = B2F_LO(hv.x), f1 = B2F_HI(hv.x);
            float f2 = B2F_LO(hv.y), f3 = B2F_HI(hv.y);
            float f4 = B2F_LO(hv.z), f5 = B2F_HI(hv.z);
            float f6 = B2F_LO(hv.w), f7 = B2F_HI(hv.w);
            float s1 = ((f0 + f1) + (f2 + f3)) + ((f4 + f5) + (f6 + f7));
            float s2 = ((f0*f0 + f1*f1) + (f2*f2 + f3*f3)) + ((f4*f4 + f5*f5) + (f6*f6 + f7*f7));
#pragma unroll
            for (int mk = 1; mk <= 16; mk <<= 1) {   // reduce within 32-lane half
                s1 += __shfl_xor(s1, mk);
                s2 += __shfl_xor(s2, mk);
            }
            float mu = s1 * (1.f / 256.f);
            float var = s2 * (1.f / 256.f) - mu * mu;
            float rs = rsqrtf(var + 1e-5f);
            int jb = (slot ^ (e & 15)) * 8;
            float4 g0 = *(const float4*)&ln_g[jb];
            float4 g1 = *(const float4*)&ln_g[jb + 4];
            float4 bb0 = *(const float4*)&ln_b[jb];
            float4 bb1 = *(const float4*)&ln_b[jb + 4];
            float n0 = fmaf((f0 - mu) * rs, g0.x, bb0.x);
            float n1 = fmaf((f1 - mu) * rs, g0.y, bb0.y);
            float n2 = fmaf((f2 - mu) * rs, g0.z, bb0.z);
            float n3 = fmaf((f3 - mu) * rs, g0.w, bb0.w);
            float n4 = fmaf((f4 - mu) * rs, g1.x, bb1.x);
            float n5 = fmaf((f5 - mu) * rs, g1.y, bb1.y);
            float n6 = fmaf((f6 - mu) * rs, g1.z, bb1.z);
            float n7 = fmaf((f7 - mu) * rs, g1.w, bb1.w);
            uint4 pv;
            pv.x = (unsigned)f2bf(n0) | ((unsigned)f2bf(n1) << 16);
            pv.y = (unsigned)f2bf(n2) | ((unsigned)f2bf(n3) << 16);
            pv.z = (unsigned)f2bf(n4) | ((unsigned)f2bf(n5) << 16);
            pv.w = (unsigned)f2bf(n6) | ((unsigned)f2bf(n7) << 16);
            *(uint4*)&xhb[e * 256 + (byte >> 1)] = pv;
        }
        __syncthreads();   // (E)

        // ---- GEMM2: K=256 over hn ----
#pragma unroll
        for (int mt = 0; mt < 4; mt++)
#pragma unroll
            for (int ntl = 0; ntl < 4; ntl++) {
                f32x4 a;
#pragma unroll
                for (int r = 0; r < 4; r++) a[r] = b2v[ntl];
                acc[mt][ntl] = a;
            }
#pragma unroll
        for (int ks = 0; ks < 8; ks++) {
            bf8_t bfr[4];
#pragma unroll
            for (int ntl = 0; ntl < 4; ntl++)
                bfr[ntl] = *(const bf8_t*)&w2f[(((w * 4 + ntl) * 8 + ks) * 64 + l) * 8];
            FragU a[4];
#pragma unroll
            for (int mt = 0; mt < 4; mt++) {
                int i = mt * 16 + m16;
                int bir0 = (ks * 64 + 8 * g) ^ ((i & 15) << 4);
                int bir1 = (ks * 64 + 32 + 8 * g) ^ ((i & 15) << 4);
                uint2 c0 = *(const uint2*)&xhb[i * 256 + (bir0 >> 1)];
                uint2 c1 = *(const uint2*)&xhb[i * 256 + (bir1 >> 1)];
                a[mt].u[0] = c0.x; a[mt].u[1] = c0.y; a[mt].u[2] = c1.x; a[mt].u[3] = c1.y;
            }
#pragma unroll
            for (int ntl = 0; ntl < 4; ntl++)
#pragma unroll
                for (int mt = 0; mt < 4; mt++)
                    acc[mt][ntl] = __builtin_amdgcn_mfma_f32_16x16x32_bf16(
                        a[mt].f, bfr[ntl], acc[mt][ntl], 0, 0, 0);
        }

        // ---- scatter: wave w owns quarter w (j = w*64 + d) ----
        const int* barr = (w & 1) ? ibase_s : ubase_s;
#pragma unroll
        for (int mt = 0; mt < 4; mt++) {
            int4 bb = *(const int4*)&barr[mt * 16 + 4 * g];
            int bvv[4] = {bb.x, bb.y, bb.z, bb.w};
#pragma unroll
            for (int ntl = 0; ntl < 4; ntl++) {
                int d = ntl * 16 + m16;
#pragma unroll
                for (int r = 0; r < 4; r++) {
                    int v = bvv[r];
                    if (v >= 0) {
                        float val = acc[mt][ntl][r];
                        if (w == 0)      atomicAdd(&out[(v & 0x03FFFFFF) + d], val);
                        else if (w == 1) atomicAdd(&outi[(v & 0x03FFFFFF) + d], val);
                        else if (w == 2) atomicAdd(&gacc[(v >> 26) * 64 + d], val);
                        else             atomicAdd(&gacc[2048 + (v >> 26) * 64 + d], val);
                    }
                }
            }
        }
    }

    __syncthreads();
    for (int i = tid; i < 4096; i += 256) {
        float v = gacc[i];
        if (v != 0.f) atomicAdd(&glob[i], v);
    }
}

__global__ void finalize_kernel(float* __restrict__ out, const float* __restrict__ glob,
                                long out_half, long nnD, float inv_nodes, int n4) {
    int i4 = blockIdx.x * 256 + threadIdx.x;
    int stride = gridDim.x * 256;
    for (; i4 < n4; i4 += stride) {
        long i = (long)i4 * 4;
        int half = (i >= out_half) ? 1 : 0;
        long r = half ? (i - out_half) : i;
        int b = (int)(r / nnD);
        int dq = (int)(i & 63);
        float4 gv = *(const float4*)&glob[half * 2048 + b * 64 + dq];
        float4 o = ((float4*)out)[i4];
        o.x += gv.x * inv_nodes;
        o.y += gv.y * inv_nodes;
        o.z += gv.z * inv_nodes;
        o.w += gv.w * inv_nodes;
        ((float4*)out)[i4] = o;
    }
}

extern "C" void kernel_launch(void* const* d_in, const int* in_sizes, int n_in,
                              void* d_out, int out_size, void* d_ws, size_t ws_size,
                              hipStream_t stream) {
    const int* users = (const int*)d_in[0];
    const int* items = (const int*)d_in[1];
    const float* msgs = (const float*)d_in[2];
    const float* uemb = (const float*)d_in[4];
    const float* iemb = (const float*)d_in[5];
    const float* W1 = (const float*)d_in[6];
    const float* b1 = (const float*)d_in[7];
    const float* ln_g = (const float*)d_in[8];
    const float* ln_b = (const float*)d_in[9];
    const float* W2 = (const float*)d_in[10];
    const float* b2 = (const float*)d_in[11];

    float* out = (float*)d_out;
    float* glob = (float*)d_ws;                                        // 16 KB
    unsigned short* w1f = (unsigned short*)((char*)d_ws + 16384);      // 64 KB
    unsigned short* w2f = (unsigned short*)((char*)d_ws + 16384 + 65536); // 128 KB

    const int E = in_sizes[0];
    const int dh = in_sizes[7];           // 256
    const int D = dh / 4;                 // 64
    const int num_nodes = in_sizes[4] / D;
    const long out_half = (long)out_size / 2;
    const int bs = (int)(out_half / ((long)num_nodes * D));

    zero_f4_kernel<<<2048, 256, 0, stream>>>((float4*)out, out_size / 4);
    zero_f4_kernel<<<4, 256, 0, stream>>>((float4*)glob, 4096 / 4);
    convert_w_kernel<<<48, 256, 0, stream>>>(W1, W2, w1f, w2f);

    encode_mfma_kernel<<<512, 256, 0, stream>>>(
        users, items, msgs, uemb, iemb, W1, b1, ln_g, ln_b, b2,
        w1f, w2f, out, glob, E, num_nodes, bs, out_half);

    finalize_kernel<<<2048, 256, 0, stream>>>(out, glob, out_half,
                                              (long)num_nodes * 64, 1.0f / num_nodes,
                                              out_size / 4);
}

// Round 3
// 471.632 us; speedup vs baseline: 2.2590x; 1.4528x over previous
//
#include <hip/hip_runtime.h>
#include <hip/hip_bf16.h>

// EventEncoder via bf16 MFMA, W1+W2 register-pinned, bf16 embedding tables.
// D=64, d_h=256, d_in=129. 64 events/block-tile, 512 threads (8 waves),
// wave w owns output cols [w*32, w*32+32). 16x16x32 bf16 MFMA.

typedef __attribute__((ext_vector_type(8))) short bf8_t;   // 8 bf16 = 4 VGPRs
typedef __attribute__((ext_vector_type(4))) float f32x4;

union FragU { bf8_t f; unsigned int u[4]; };

static __device__ __forceinline__ unsigned short f2bf(float f) {
    unsigned int x = __float_as_uint(f);
    return (unsigned short)((x + 0x7fffu + ((x >> 16) & 1u)) >> 16);
}
#define B2F_LO(u) __uint_as_float((u) << 16)
#define B2F_HI(u) __uint_as_float((u) & 0xffff0000u)

__global__ void zero_f4_kernel(float4* p, int n4) {
    int i = blockIdx.x * 256 + threadIdx.x;
    int stride = gridDim.x * 256;
    float4 z = make_float4(0.f, 0.f, 0.f, 0.f);
    for (; i < n4; i += stride) p[i] = z;
}

// W frags (verified layout from round 2) + bf16 embedding tables.
__global__ void convert_kernel(const float* __restrict__ W1, const float* __restrict__ W2,
                               const float* __restrict__ uemb, const float* __restrict__ iemb,
                               unsigned short* __restrict__ w1f, unsigned short* __restrict__ w2f,
                               unsigned short* __restrict__ uembb, unsigned short* __restrict__ iembb,
                               int nemb4) {
    int idx = blockIdx.x * 256 + threadIdx.x;
    if (idx < 4096) {               // W1: 16 nt * 4 ks * 64 lanes
        int l = idx & 63, fr = idx >> 6;
        int ks = fr & 3, nt = fr >> 2;
        int n = nt * 16 + (l & 15), g = l >> 4;
        unsigned short v[8];
#pragma unroll
        for (int e = 0; e < 8; e++) {
            int k = ks * 32 + ((e < 4) ? (4 * g + e) : (16 + 4 * g + (e - 4)));
            v[e] = f2bf(W1[k * 256 + n]);
        }
        uint4 pk;
        pk.x = (unsigned)v[0] | ((unsigned)v[1] << 16);
        pk.y = (unsigned)v[2] | ((unsigned)v[3] << 16);
        pk.z = (unsigned)v[4] | ((unsigned)v[5] << 16);
        pk.w = (unsigned)v[6] | ((unsigned)v[7] << 16);
        *(uint4*)&w1f[idx * 8] = pk;
    } else if (idx < 12288) {       // W2: 16 nt * 8 ks * 64 lanes
        int t = idx - 4096;
        int l = t & 63, fr = t >> 6;
        int ks = fr & 7, nt = fr >> 3;
        int n = nt * 16 + (l & 15), g = l >> 4;
        unsigned short v[8];
#pragma unroll
        for (int e = 0; e < 8; e++) {
            int k = ks * 32 + ((e < 4) ? (4 * g + e) : (16 + 4 * g + (e - 4)));
            v[e] = f2bf(W2[k * 256 + n]);
        }
        uint4 pk;
        pk.x = (unsigned)v[0] | ((unsigned)v[1] << 16);
        pk.y = (unsigned)v[2] | ((unsigned)v[3] << 16);
        pk.z = (unsigned)v[4] | ((unsigned)v[5] << 16);
        pk.w = (unsigned)v[6] | ((unsigned)v[7] << 16);
        *(uint4*)&w2f[t * 8] = pk;
    }
    if (nemb4 > 0) {
        int total = gridDim.x * 256;
        for (int i = idx; i < 2 * nemb4; i += total) {
            int isU = (i < nemb4);
            int j = isU ? i : i - nemb4;
            float4 v = isU ? ((const float4*)uemb)[j] : ((const float4*)iemb)[j];
            ushort4 p;
            p.x = f2bf(v.x); p.y = f2bf(v.y); p.z = f2bf(v.z); p.w = f2bf(v.w);
            unsigned short* dst = isU ? uembb : iembb;
            *(ushort4*)&dst[(long)j * 4] = p;
        }
    }
}

__global__ __launch_bounds__(512, 2)
void encode_mfma_kernel(const int* __restrict__ users, const int* __restrict__ items,
                        const float* __restrict__ msgs,
                        const float* __restrict__ uemb, const float* __restrict__ iemb,
                        const unsigned short* __restrict__ uembb, const unsigned short* __restrict__ iembb,
                        const float* __restrict__ W1, const float* __restrict__ b1,
                        const float* __restrict__ ln_g, const float* __restrict__ ln_b,
                        const float* __restrict__ b2,
                        const unsigned short* __restrict__ w1f, const unsigned short* __restrict__ w2f,
                        float* __restrict__ out, float* __restrict__ glob,
                        int E, int num_nodes, int bs, long out_half, int usebf) {
    // x phase: rows of 128 bf16 (256B, swizzle (e&7)<<4); h phase: rows of 256 bf16 (512B, swizzle (e&15)<<4)
    __shared__ __align__(16) unsigned short xhb[64 * 256];   // 32 KB
    __shared__ __align__(16) float gacc[4096];               // 16 KB  [2][32][64]
    __shared__ __align__(16) float msgs_s[64];
    __shared__ __align__(16) int ubase_s[64], ibase_s[64];   // base | (b<<26)

    const int tid = threadIdx.x;
    const int w = tid >> 6;         // wave 0..7 -> cols [w*32, w*32+32)
    const int l = tid & 63;
    const int g = l >> 4;
    const int m16 = l & 15;
    const int nnD = num_nodes * 64;

    for (int i = tid; i < 4096; i += 512) gacc[i] = 0.f;

    // register-pinned W1/W2 fragments: global nt = w*2 + ntl
    bf8_t w1frag[2][4], w2frag[2][8];
#pragma unroll
    for (int ntl = 0; ntl < 2; ntl++) {
        int nt = w * 2 + ntl;
#pragma unroll
        for (int ks = 0; ks < 4; ks++)
            w1frag[ntl][ks] = *(const bf8_t*)&w1f[((nt * 4 + ks) * 64 + l) * 8];
#pragma unroll
        for (int ks = 0; ks < 8; ks++)
            w2frag[ntl][ks] = *(const bf8_t*)&w2f[((nt * 8 + ks) * 64 + l) * 8];
    }

    float b1v[2], w128v[2], b2v[2];
#pragma unroll
    for (int ntl = 0; ntl < 2; ntl++) {
        int j = w * 32 + ntl * 16 + m16;
        b1v[ntl] = b1[j];
        w128v[ntl] = W1[128 * 256 + j];
        b2v[ntl] = b2[j];
    }
    float* outi = out + out_half;

    const int nTiles = (E + 63) >> 6;
    for (int tile = blockIdx.x; tile < nTiles; tile += gridDim.x) {
        const int e0 = tile << 6;
        __syncthreads();   // (A)

        if (tid < 64) {
            int ev = e0 + tid;
            if (ev < E) {
                int u = users[ev], it = items[ev];
                int ub = u % bs, un = u / bs, ib = it % bs, in_ = it / bs;
                ubase_s[tid] = (ub * nnD + un * 64) | (ub << 26);
                ibase_s[tid] = (ib * nnD + in_ * 64) | (ib << 26);
                msgs_s[tid] = msgs[ev];
            } else {
                ubase_s[tid] = -1; ibase_s[tid] = -1; msgs_s[tid] = 0.f;
            }
        }
        // ---- stage x: 64 rows x 16 chunks of 8 bf16 (16B) ----
        for (int idx = tid; idx < 1024; idx += 512) {
            int e = idx >> 4, q = idx & 15;
            int ev = e0 + e;
            uint4 v = make_uint4(0u, 0u, 0u, 0u);
            if (ev < E) {
                if (usebf) {
                    if (q < 8) { int u = users[ev] % num_nodes; v = *(const uint4*)&uembb[(long)u * 64 + q * 8]; }
                    else       { int it = items[ev] % num_nodes; v = *(const uint4*)&iembb[(long)it * 64 + (q - 8) * 8]; }
                } else {
                    const float* src; long base;
                    if (q < 8) { int u = users[ev] % num_nodes; src = uemb; base = (long)u * 64 + q * 8; }
                    else       { int it = items[ev] % num_nodes; src = iemb; base = (long)it * 64 + (q - 8) * 8; }
                    float4 a0 = *(const float4*)&src[base];
                    float4 a1 = *(const float4*)&src[base + 4];
                    v.x = (unsigned)f2bf(a0.x) | ((unsigned)f2bf(a0.y) << 16);
                    v.y = (unsigned)f2bf(a0.z) | ((unsigned)f2bf(a0.w) << 16);
                    v.z = (unsigned)f2bf(a1.x) | ((unsigned)f2bf(a1.y) << 16);
                    v.w = (unsigned)f2bf(a1.z) | ((unsigned)f2bf(a1.w) << 16);
                }
            }
            int byte = (q * 16) ^ ((e & 7) << 4);
            *(uint4*)&xhb[e * 128 + (byte >> 1)] = v;
        }
        __syncthreads();   // (B)

        // ---- GEMM1: K=128, init b1 + msg*W1[128,:] ----
        f32x4 acc[4][2];
#pragma unroll
        for (int mt = 0; mt < 4; mt++) {
            const float* mgp = &msgs_s[mt * 16 + 4 * g];
            float mg[4] = {mgp[0], mgp[1], mgp[2], mgp[3]};
#pragma unroll
            for (int ntl = 0; ntl < 2; ntl++) {
                f32x4 a;
#pragma unroll
                for (int r = 0; r < 4; r++) a[r] = fmaf(mg[r], w128v[ntl], b1v[ntl]);
                acc[mt][ntl] = a;
            }
        }
#pragma unroll
        for (int ks = 0; ks < 4; ks++) {
            FragU a[4];
#pragma unroll
            for (int mt = 0; mt < 4; mt++) {
                int i = mt * 16 + m16;
                int bir0 = (ks * 64 + 8 * g) ^ ((i & 7) << 4);
                int bir1 = (ks * 64 + 32 + 8 * g) ^ ((i & 7) << 4);
                uint2 c0 = *(const uint2*)&xhb[i * 128 + (bir0 >> 1)];
                uint2 c1 = *(const uint2*)&xhb[i * 128 + (bir1 >> 1)];
                a[mt].u[0] = c0.x; a[mt].u[1] = c0.y; a[mt].u[2] = c1.x; a[mt].u[3] = c1.y;
            }
#pragma unroll
            for (int ntl = 0; ntl < 2; ntl++)
#pragma unroll
                for (int mt = 0; mt < 4; mt++)
                    acc[mt][ntl] = __builtin_amdgcn_mfma_f32_16x16x32_bf16(
                        a[mt].f, w1frag[ntl][ks], acc[mt][ntl], 0, 0, 0);
        }
        __syncthreads();   // (C)

        // ---- epilogue: h -> bf16, rows 256 bf16, swizzle (e&15)<<4 ----
#pragma unroll
        for (int mt = 0; mt < 4; mt++)
#pragma unroll
            for (int ntl = 0; ntl < 2; ntl++)
#pragma unroll
                for (int r = 0; r < 4; r++) {
                    int e = mt * 16 + 4 * g + r;
                    int j = w * 32 + ntl * 16 + m16;
                    int byte = (2 * j) ^ ((e & 15) << 4);
                    xhb[e * 256 + (byte >> 1)] = f2bf(acc[mt][ntl][r]);
                }
        __syncthreads();   // (D)

        // ---- LayerNorm: wave w rows [w*8, w*8+8), 2 rows/iter ----
#pragma unroll
        for (int it = 0; it < 4; it++) {
            int e = w * 8 + it * 2 + (l >> 5);
            int slot = l & 31;
            int byte = (slot * 16) ^ ((e & 15) << 4);
            uint4 hv = *(const uint4*)&xhb[e * 256 + (byte >> 1)];
            float f0 = B2F_LO(hv.x), f1 = B2F_HI(hv.x);
            float f2 = B2F_LO(hv.y), f3 = B2F_HI(hv.y);
            float f4 = B2F_LO(hv.z), f5 = B2F_HI(hv.z);
            float f6 = B2F_LO(hv.w), f7 = B2F_HI(hv.w);
            float s1 = ((f0 + f1) + (f2 + f3)) + ((f4 + f5) + (f6 + f7));
            float s2 = ((f0*f0 + f1*f1) + (f2*f2 + f3*f3)) + ((f4*f4 + f5*f5) + (f6*f6 + f7*f7));
#pragma unroll
            for (int mk = 1; mk <= 16; mk <<= 1) {
                s1 += __shfl_xor(s1, mk);
                s2 += __shfl_xor(s2, mk);
            }
            float mu = s1 * (1.f / 256.f);
            float var = s2 * (1.f / 256.f) - mu * mu;
            float rs = rsqrtf(var + 1e-5f);
            int jb = (slot ^ (e & 15)) * 8;
            float4 g0 = *(const float4*)&ln_g[jb];
            float4 g1 = *(const float4*)&ln_g[jb + 4];
            float4 bb0 = *(const float4*)&ln_b[jb];
            float4 bb1 = *(const float4*)&ln_b[jb + 4];
            float n0 = fmaf((f0 - mu) * rs, g0.x, bb0.x);
            float n1 = fmaf((f1 - mu) * rs, g0.y, bb0.y);
            float n2 = fmaf((f2 - mu) * rs, g0.z, bb0.z);
            float n3 = fmaf((f3 - mu) * rs, g0.w, bb0.w);
            float n4 = fmaf((f4 - mu) * rs, g1.x, bb1.x);
            float n5 = fmaf((f5 - mu) * rs, g1.y, bb1.y);
            float n6 = fmaf((f6 - mu) * rs, g1.z, bb1.z);
            float n7 = fmaf((f7 - mu) * rs, g1.w, bb1.w);
            uint4 pv;
            pv.x = (unsigned)f2bf(n0) | ((unsigned)f2bf(n1) << 16);
            pv.y = (unsigned)f2bf(n2) | ((unsigned)f2bf(n3) << 16);
            pv.z = (unsigned)f2bf(n4) | ((unsigned)f2bf(n5) << 16);
            pv.w = (unsigned)f2bf(n6) | ((unsigned)f2bf(n7) << 16);
            *(uint4*)&xhb[e * 256 + (byte >> 1)] = pv;
        }
        __syncthreads();   // (E)

        // ---- GEMM2: K=256, W2 from registers ----
#pragma unroll
        for (int mt = 0; mt < 4; mt++)
#pragma unroll
            for (int ntl = 0; ntl < 2; ntl++) {
                f32x4 a;
#pragma unroll
                for (int r = 0; r < 4; r++) a[r] = b2v[ntl];
                acc[mt][ntl] = a;
            }
#pragma unroll
        for (int ks = 0; ks < 8; ks++) {
            FragU a[4];
#pragma unroll
            for (int mt = 0; mt < 4; mt++) {
                int i = mt * 16 + m16;
                int bir0 = (ks * 64 + 8 * g) ^ ((i & 15) << 4);
                int bir1 = (ks * 64 + 32 + 8 * g) ^ ((i & 15) << 4);
                uint2 c0 = *(const uint2*)&xhb[i * 256 + (bir0 >> 1)];
                uint2 c1 = *(const uint2*)&xhb[i * 256 + (bir1 >> 1)];
                a[mt].u[0] = c0.x; a[mt].u[1] = c0.y; a[mt].u[2] = c1.x; a[mt].u[3] = c1.y;
            }
#pragma unroll
            for (int ntl = 0; ntl < 2; ntl++)
#pragma unroll
                for (int mt = 0; mt < 4; mt++)
                    acc[mt][ntl] = __builtin_amdgcn_mfma_f32_16x16x32_bf16(
                        a[mt].f, w2frag[ntl][ks], acc[mt][ntl], 0, 0, 0);
        }

        // ---- scatter: waves 0,1->uu  2,3->iu  4,5->ug(LDS)  6,7->ig(LDS) ----
        const int q = w >> 1;
        const int dbase = (w & 1) * 32;
        const int* barr = (q & 1) ? ibase_s : ubase_s;
#pragma unroll
        for (int mt = 0; mt < 4; mt++) {
            int4 bb = *(const int4*)&barr[mt * 16 + 4 * g];
            int bvv[4] = {bb.x, bb.y, bb.z, bb.w};
#pragma unroll
            for (int ntl = 0; ntl < 2; ntl++) {
                int d = dbase + ntl * 16 + m16;
#pragma unroll
                for (int r = 0; r < 4; r++) {
                    int v = bvv[r];
                    if (v >= 0) {
                        float val = acc[mt][ntl][r];
                        if (q == 0)      atomicAdd(&out[(v & 0x03FFFFFF) + d], val);
                        else if (q == 1) atomicAdd(&outi[(v & 0x03FFFFFF) + d], val);
                        else if (q == 2) atomicAdd(&gacc[(v >> 26) * 64 + d], val);
                        else             atomicAdd(&gacc[2048 + (v >> 26) * 64 + d], val);
                    }
                }
            }
        }
    }

    __syncthreads();
    for (int i = tid; i < 4096; i += 512) {
        float v = gacc[i];
        if (v != 0.f) atomicAdd(&glob[i], v);
    }
}

__global__ void finalize_kernel(float* __restrict__ out, const float* __restrict__ glob,
                                long out_half, long nnD, float inv_nodes, int n4) {
    int i4 = blockIdx.x * 256 + threadIdx.x;
    int stride = gridDim.x * 256;
    for (; i4 < n4; i4 += stride) {
        long i = (long)i4 * 4;
        int half = (i >= out_half) ? 1 : 0;
        long r = half ? (i - out_half) : i;
        int b = (int)(r / nnD);
        int dq = (int)(i & 63);
        float4 gv = *(const float4*)&glob[half * 2048 + b * 64 + dq];
        float4 o = ((float4*)out)[i4];
        o.x += gv.x * inv_nodes;
        o.y += gv.y * inv_nodes;
        o.z += gv.z * inv_nodes;
        o.w += gv.w * inv_nodes;
        ((float4*)out)[i4] = o;
    }
}

extern "C" void kernel_launch(void* const* d_in, const int* in_sizes, int n_in,
                              void* d_out, int out_size, void* d_ws, size_t ws_size,
                              hipStream_t stream) {
    const int* users = (const int*)d_in[0];
    const int* items = (const int*)d_in[1];
    const float* msgs = (const float*)d_in[2];
    const float* uemb = (const float*)d_in[4];
    const float* iemb = (const float*)d_in[5];
    const float* W1 = (const float*)d_in[6];
    const float* b1 = (const float*)d_in[7];
    const float* ln_g = (const float*)d_in[8];
    const float* ln_b = (const float*)d_in[9];
    const float* W2 = (const float*)d_in[10];
    const float* b2 = (const float*)d_in[11];

    const int E = in_sizes[0];
    const int dh = in_sizes[7];           // 256
    const int D = dh / 4;                 // 64
    const int num_nodes = in_sizes[4] / D;
    const long out_half = (long)out_size / 2;
    const int bs = (int)(out_half / ((long)num_nodes * D));

    float* out = (float*)d_out;
    float* glob = (float*)d_ws;                                           // 16 KB
    unsigned short* w1f = (unsigned short*)((char*)d_ws + 16384);         // 64 KB
    unsigned short* w2f = (unsigned short*)((char*)d_ws + 16384 + 65536); // 128 KB
    size_t embb_off = 16384 + 65536 + 131072;                             // 212992
    size_t embb_bytes = (size_t)num_nodes * 64 * 2;
    int usebf = (ws_size >= embb_off + 2 * embb_bytes) ? 1 : 0;
    unsigned short* uembb = usebf ? (unsigned short*)((char*)d_ws + embb_off) : nullptr;
    unsigned short* iembb = usebf ? (unsigned short*)((char*)d_ws + embb_off + embb_bytes) : nullptr;
    int nemb4 = usebf ? (num_nodes * 16) : 0;

    zero_f4_kernel<<<2048, 256, 0, stream>>>((float4*)out, out_size / 4);
    zero_f4_kernel<<<4, 256, 0, stream>>>((float4*)glob, 4096 / 4);
    convert_kernel<<<256, 256, 0, stream>>>(W1, W2, uemb, iemb, w1f, w2f, uembb, iembb, nemb4);

    encode_mfma_kernel<<<256, 512, 0, stream>>>(
        users, items, msgs, uemb, iemb, uembb, iembb,
        W1, b1, ln_g, ln_b, b2, w1f, w2f, out, glob,
        E, num_nodes, bs, out_half, usebf);

    finalize_kernel<<<2048, 256, 0, stream>>>(out, glob, out_half,
                                              (long)num_nodes * 64, 1.0f / num_nodes,
                                              out_size / 4);
}